// Round 2
// baseline (253.785 us; speedup 1.0000x reference)
//
#include <hip/hip_runtime.h>
#include <math.h>

namespace {
constexpr int kB  = 64;
constexpr int kT  = 1024;
constexpr int kK  = 512;
constexpr int kC  = 8;           // chunks over T (one wave per chunk)
constexpr int kL  = kT / kC;     // 128 steps per chunk
constexpr int kKB = 64;          // k-values per block (= lanes per wave)
constexpr int kPF = 8;           // prefetch depth within a chunk scan
constexpr float kDT = 0.001f;
}

// Two-sweep chunked linear scan, one block per (b, k-group of 64).
// 512 threads = 8 waves; wave c handles time chunk c. 16 waves/CU of TLP
// replaces the failed 2-waves/CU + software-pipeline approach.
// Phase A: per-chunk scan from zero state -> final state F_c in LDS.
// Combine: S_c = A^L * S_{c-1} + F_{c-1}  (A^L via 7 exact 2x2 squarings).
// Phase B: re-scan chunk from true S_c, write outputs. Input is read twice
// (402 MB raw) but the re-read should largely hit the 256 MiB L3.
__global__ __launch_bounds__(kKB * kC, 4) void alpha_scan2(
    const float* __restrict__ in,
    const float* __restrict__ init_level,
    const float* __restrict__ tau,
    float* __restrict__ out)
{
    __shared__ float sF0[kC][kKB];
    __shared__ float sF1[kC][kKB];

    const int lane = threadIdx.x & 63;      // k within group
    const int c    = threadIdx.x >> 6;      // chunk index (wave-uniform)
    const int kg   = blockIdx.x & 7;        // k group: 512/64 = 8
    const int b    = blockIdx.x >> 3;       // batch
    const int k    = kg * kKB + lane;

    // Per-feature coefficients (same arithmetic as reference).
    const float tc      = fmaxf(tau[k], 1e-8f);
    const float dt_tau  = kDT / tc;
    const float dt_tau2 = dt_tau / tc;
    const float e       = expf(-dt_tau);

    const float a00 = e * (1.0f - dt_tau);
    const float a01 = e * (-dt_tau2);
    const float a10 = e * kDT;
    const float a11 = e * (1.0f + dt_tau);
    const float b0  = e * dt_tau2;
    const float b1  = 1.0f - e * (1.0f + dt_tau);

    const float* __restrict__ pin =
        in + ((size_t)b * kT + (size_t)c * kL) * kK + k;

    // ---- Phase A: local scan from zero state; final state only ----
    float x0 = 0.0f, x1 = 0.0f;
    {
        float buf[kPF];
        #pragma unroll
        for (int i = 0; i < kPF; ++i) buf[i] = pin[(size_t)i * kK];
        for (int t0 = 0; t0 < kL - kPF; t0 += kPF) {
            const float* __restrict__ pld = pin + (size_t)(t0 + kPF) * kK;
            #pragma unroll
            for (int i = 0; i < kPF; ++i) {
                const float u = buf[i];
                buf[i] = pld[(size_t)i * kK];
                const float n0 = fmaf(a00, x0, fmaf(a01, x1, b0 * u));
                const float n1 = fmaf(a10, x0, fmaf(a11, x1, b1 * u));
                x0 = n0; x1 = n1;
            }
        }
        #pragma unroll
        for (int i = 0; i < kPF; ++i) {
            const float u = buf[i];
            const float n0 = fmaf(a00, x0, fmaf(a01, x1, b0 * u));
            const float n1 = fmaf(a10, x0, fmaf(a11, x1, b1 * u));
            x0 = n0; x1 = n1;
        }
    }
    sF0[c][lane] = x0;
    sF1[c][lane] = x1;
    __syncthreads();

    // ---- A^L = A^128 via 7 squarings (exact 2x2) ----
    float m00 = a00, m01 = a01, m10 = a10, m11 = a11;
    #pragma unroll
    for (int s = 0; s < 7; ++s) {
        const float t00 = fmaf(m00, m00, m01 * m10);
        const float t01 = fmaf(m00, m01, m01 * m11);
        const float t10 = fmaf(m10, m00, m11 * m10);
        const float t11 = fmaf(m10, m01, m11 * m11);
        m00 = t00; m01 = t01; m10 = t10; m11 = t11;
    }

    // ---- Combine: true entry state S_c for this chunk ----
    float s0 = 0.0f, s1 = init_level[k];
    for (int cp = 0; cp < c; ++cp) {          // wave-uniform trip count
        const float f0 = sF0[cp][lane];
        const float f1 = sF1[cp][lane];
        const float n0 = fmaf(m00, s0, fmaf(m01, s1, f0));
        const float n1 = fmaf(m10, s0, fmaf(m11, s1, f1));
        s0 = n0; s1 = n1;
    }

    // ---- Phase B: true scan from S_c, write outputs ----
    x0 = s0; x1 = s1;
    float* __restrict__ pout =
        out + ((size_t)b * kT + (size_t)c * kL) * kK + k;
    {
        float buf[kPF];
        #pragma unroll
        for (int i = 0; i < kPF; ++i) buf[i] = pin[(size_t)i * kK];
        for (int t0 = 0; t0 < kL - kPF; t0 += kPF) {
            const float* __restrict__ pld = pin  + (size_t)(t0 + kPF) * kK;
            float* __restrict__ pst       = pout + (size_t)t0 * kK;
            #pragma unroll
            for (int i = 0; i < kPF; ++i) {
                const float u = buf[i];
                buf[i] = pld[(size_t)i * kK];
                const float n0 = fmaf(a00, x0, fmaf(a01, x1, b0 * u));
                const float n1 = fmaf(a10, x0, fmaf(a11, x1, b1 * u));
                x0 = n0; x1 = n1;
                pst[(size_t)i * kK] = n1;
            }
        }
        float* __restrict__ pst = pout + (size_t)(kL - kPF) * kK;
        #pragma unroll
        for (int i = 0; i < kPF; ++i) {
            const float u = buf[i];
            const float n0 = fmaf(a00, x0, fmaf(a01, x1, b0 * u));
            const float n1 = fmaf(a10, x0, fmaf(a11, x1, b1 * u));
            x0 = n0; x1 = n1;
            pst[(size_t)i * kK] = n1;
        }
    }
}

extern "C" void kernel_launch(void* const* d_in, const int* in_sizes, int n_in,
                              void* d_out, int out_size, void* d_ws, size_t ws_size,
                              hipStream_t stream) {
    const float* in  = (const float*)d_in[0];   // [64,1024,512] fp32
    const float* il  = (const float*)d_in[1];   // [512] fp32
    const float* tau = (const float*)d_in[2];   // [512] fp32
    float* out = (float*)d_out;                 // [64,1024,512] fp32

    dim3 block(kKB * kC);                       // 512 threads = 8 waves
    dim3 grid(kB * (kK / kKB));                 // 64 b x 8 k-groups = 512 blocks
    alpha_scan2<<<grid, block, 0, stream>>>(in, il, tau, out);
}